// Round 1
// 1616.933 us; speedup vs baseline: 1.0528x; 1.0528x over previous
//
#include <hip/hip_runtime.h>
#include <hip/hip_bf16.h>

typedef __attribute__((ext_vector_type(8))) __bf16 bf16x8;
typedef __attribute__((ext_vector_type(4))) float f32x4;

#define OUTC   200000
#define NHEAD  20002
#define NW1    40000
#define NW2    140000
#define MROWS  1024
#define HID    1024

__device__ __forceinline__ unsigned short f2bf(float f) {
  union { float f; unsigned u; } a; a.f = f;
  unsigned u = a.u;
  return (unsigned short)((u + 0x7fffu + ((u >> 16) & 1u)) >> 16);
}

// ---------------- fp32 -> bf16 convert (vectorized) ----------------
__global__ void cvt_kernel(const float* __restrict__ in, unsigned short* __restrict__ o, int n4) {
  int i = blockIdx.x * blockDim.x + threadIdx.x;
  if (i >= n4) return;
  float4 v = ((const float4*)in)[i];
  ushort4 r;
  r.x = f2bf(v.x); r.y = f2bf(v.y); r.z = f2bf(v.z); r.w = f2bf(v.w);
  ((ushort4*)o)[i] = r;
}

__device__ __forceinline__ void load16(const unsigned short* g, unsigned short* l) {
  __builtin_amdgcn_global_load_lds(
      (const __attribute__((address_space(1))) unsigned int*)g,
      (__attribute__((address_space(3))) unsigned int*)l, 16, 0, 0);
}

// ---------------- m97-style bf16 GEMM, C = A(1024xK) * B(NxK)^T ----------------
// Grid: blockIdx.x = mtile (8, inner/fastest -> B-panel shared across XCDs),
//       blockIdx.y = ntile.
// EPI 0: head  -> out cols [0,20000), cols 20000/20001 -> cluster[r*2+k]
// EPI 1: proj  -> bf16 ws (row-major 1024 x N)
// EPI 2: stats-only -> per-(ntile,row) (max, sumexp); NO out writes
// EPI 3: write -> out[r, cbase+c] = acc + scal[r]  (normalized tail logits)
template<int EPI>
__launch_bounds__(256)
__global__ void gemm_bt(const unsigned short* __restrict__ A,
                        const unsigned short* __restrict__ B,
                        int N, int K,
                        float* __restrict__ out,
                        unsigned short* __restrict__ bout,
                        float* __restrict__ cluster,
                        float2* __restrict__ stats,
                        const float* __restrict__ scal,
                        int cbase) {
  __shared__ unsigned short As[128 * 64];
  __shared__ unsigned short Bs[128 * 64];
  __shared__ float sred[128 * 4];

  const int tid  = threadIdx.x;
  const int lane = tid & 63;
  const int w    = tid >> 6;
  const int wm   = w >> 1, wn = w & 1;
  const int l15  = lane & 15, quad = lane >> 4;
  const int mtile = blockIdx.x, ntile = blockIdx.y;
  const int row0 = mtile * 128, col0 = ntile * 128;

  const int srow = tid >> 3;   // 0..31
  const int sgrp = tid & 7;    // 16B group within a 64-elem row

  f32x4 acc[4][4] = {};

  for (int k0 = 0; k0 < K; k0 += 64) {
#pragma unroll
    for (int p = 0; p < 4; ++p) {
      int r = p * 32 + srow;
      int c = ((sgrp ^ (r & 7)) << 3);
      load16(A + (size_t)(row0 + r) * K + k0 + c, As + (size_t)(p * 256 + tid) * 8);
    }
#pragma unroll
    for (int p = 0; p < 4; ++p) {
      int r = p * 32 + srow;
      int gn = col0 + r; if (gn > N - 1) gn = N - 1;
      int c = ((sgrp ^ (r & 7)) << 3);
      load16(B + (size_t)gn * K + k0 + c, Bs + (size_t)(p * 256 + tid) * 8);
    }
    __syncthreads();   // drains vmcnt (global_load_lds) per m97 structure
#pragma unroll
    for (int ks = 0; ks < 64; ks += 32) {
      bf16x8 af[4], bfr[4];
#pragma unroll
      for (int i = 0; i < 4; ++i) {
        int r = wm * 64 + i * 16 + l15;
        int g = (ks >> 3) + quad;
        af[i] = *(const bf16x8*)(As + r * 64 + ((g ^ (r & 7)) << 3));
      }
#pragma unroll
      for (int j = 0; j < 4; ++j) {
        int n = wn * 64 + j * 16 + l15;
        int g = (ks >> 3) + quad;
        bfr[j] = *(const bf16x8*)(Bs + n * 64 + ((g ^ (n & 7)) << 3));
      }
#pragma unroll
      for (int i = 0; i < 4; ++i)
#pragma unroll
        for (int j = 0; j < 4; ++j)
          acc[i][j] = __builtin_amdgcn_mfma_f32_16x16x32_bf16(af[i], bfr[j], acc[i][j], 0, 0, 0);
    }
    __syncthreads();
  }

  // ---------------- epilogue ----------------
  if (EPI == 0) {
#pragma unroll
    for (int i = 0; i < 4; ++i)
#pragma unroll
      for (int comp = 0; comp < 4; ++comp) {
        int r = row0 + wm * 64 + i * 16 + quad * 4 + comp;
#pragma unroll
        for (int j = 0; j < 4; ++j) {
          int c = col0 + wn * 64 + j * 16 + l15;
          float v = acc[i][j][comp];
          if (c < 20000) out[(size_t)r * OUTC + c] = v;
          else if (c < NHEAD) cluster[r * 2 + (c - 20000)] = v;
        }
      }
  } else if (EPI == 1) {
#pragma unroll
    for (int i = 0; i < 4; ++i)
#pragma unroll
      for (int comp = 0; comp < 4; ++comp) {
        int r = row0 + wm * 64 + i * 16 + quad * 4 + comp;
#pragma unroll
        for (int j = 0; j < 4; ++j) {
          int c = col0 + wn * 64 + j * 16 + l15;
          bout[(size_t)r * N + c] = f2bf(acc[i][j][comp]);
        }
      }
  } else if (EPI == 2) {
    // stats-only: per-(ntile,row) max & sumexp, no logit writes
#pragma unroll
    for (int i = 0; i < 4; ++i)
#pragma unroll
      for (int comp = 0; comp < 4; ++comp) {
        float vv[4];
        float m = -INFINITY;
#pragma unroll
        for (int j = 0; j < 4; ++j) {
          int c = col0 + wn * 64 + j * 16 + l15;
          float v = acc[i][j][comp];
          vv[j] = v;
          if (c < N) m = fmaxf(m, v);
        }
#pragma unroll
        for (int off = 1; off < 16; off <<= 1) m = fmaxf(m, __shfl_xor(m, off, 64));
        float s = 0.f;
#pragma unroll
        for (int j = 0; j < 4; ++j) {
          int c = col0 + wn * 64 + j * 16 + l15;
          if (c < N) s += __expf(vv[j] - m);
        }
#pragma unroll
        for (int off = 1; off < 16; off <<= 1) s += __shfl_xor(s, off, 64);
        if (l15 == 0) {
          int rt = wm * 64 + i * 16 + quad * 4 + comp;
          sred[(rt * 2 + wn) * 2 + 0] = m;
          sred[(rt * 2 + wn) * 2 + 1] = s;
        }
      }
    __syncthreads();
    if (tid < 128) {
      float m0 = sred[(tid * 2 + 0) * 2 + 0], l0 = sred[(tid * 2 + 0) * 2 + 1];
      float m1 = sred[(tid * 2 + 1) * 2 + 0], l1 = sred[(tid * 2 + 1) * 2 + 1];
      float mm = fmaxf(m0, m1);
      float ll = (m0 == -INFINITY ? 0.f : l0 * __expf(m0 - mm)) +
                 (m1 == -INFINITY ? 0.f : l1 * __expf(m1 - mm));
      stats[(size_t)ntile * 1024 + row0 + tid] = make_float2(mm, ll);
    }
  } else {
    // write pass: normalized tail logits in one store (no fixup re-read)
#pragma unroll
    for (int i = 0; i < 4; ++i)
#pragma unroll
      for (int comp = 0; comp < 4; ++comp) {
        int r = row0 + wm * 64 + i * 16 + quad * 4 + comp;
        float s = scal[r];
#pragma unroll
        for (int j = 0; j < 4; ++j) {
          int c = col0 + wn * 64 + j * 16 + l15;
          if (c < N) out[(size_t)r * OUTC + cbase + c] = acc[i][j][comp] + s;
        }
      }
  }
}

// ---------------- per-row stats merge: scal[r] = cluster[r,ci] - m - log(l) ----------------
__global__ void merge_stats(const float2* __restrict__ stats, int T,
                            const float* __restrict__ cluster, int ci,
                            float* __restrict__ scal) {
  int r = blockIdx.x * 4 + (threadIdx.x >> 6);
  int lane = threadIdx.x & 63;
  float m = -INFINITY, l = 0.f;
  for (int t = lane; t < T; t += 64) {
    float2 s = stats[(size_t)t * 1024 + r];
    float mn = fmaxf(m, s.x);
    l = l * __expf(m - mn) + s.y * __expf(s.x - mn);
    m = mn;
  }
  for (int off = 1; off < 64; off <<= 1) {
    float mo = __shfl_xor(m, off, 64);
    float lo = __shfl_xor(l, off, 64);
    float mn = fmaxf(m, mo);
    l = l * __expf(m - mn) + lo * __expf(mo - mn);
    m = mn;
  }
  if (lane == 0) scal[r] = cluster[r * 2 + ci] - m - logf(l);
}

extern "C" void kernel_launch(void* const* d_in, const int* in_sizes, int n_in,
                              void* d_out, int out_size, void* d_ws, size_t ws_size,
                              hipStream_t stream) {
  const float* x   = (const float*)d_in[0];
  const float* Wh  = (const float*)d_in[1];
  const float* Wp1 = (const float*)d_in[2];
  const float* Wt1 = (const float*)d_in[3];
  const float* Wp2 = (const float*)d_in[4];
  const float* Wt2 = (const float*)d_in[5];
  float* out = (float*)d_out;

  char* ws = (char*)d_ws;
  size_t off = 0;
  auto alloc = [&](size_t bytes) {
    void* p = ws + off;
    off += (bytes + 255) & ~(size_t)255;
    return p;
  };
  unsigned short* xb   = (unsigned short*)alloc((size_t)MROWS * HID * 2);
  unsigned short* whb  = (unsigned short*)alloc((size_t)NHEAD * HID * 2);
  unsigned short* wp1b = (unsigned short*)alloc((size_t)512 * HID * 2);
  unsigned short* wt1b = (unsigned short*)alloc((size_t)NW1 * 512 * 2);
  unsigned short* wp2b = (unsigned short*)alloc((size_t)256 * HID * 2);
  unsigned short* wt2b = (unsigned short*)alloc((size_t)NW2 * 256 * 2);
  unsigned short* p1b  = (unsigned short*)alloc((size_t)MROWS * 512 * 2);
  unsigned short* p2b  = (unsigned short*)alloc((size_t)MROWS * 256 * 2);
  float*  cluster = (float*)alloc((size_t)MROWS * 2 * 4);
  float2* stats1  = (float2*)alloc((size_t)313 * 1024 * 8);
  float2* stats2  = (float2*)alloc((size_t)1094 * 1024 * 8);
  float*  scal1   = (float*)alloc(1024 * 4);
  float*  scal2   = (float*)alloc(1024 * 4);

  auto cvt = [&](const float* src, unsigned short* dst, size_t n) {
    int n4 = (int)(n / 4);
    cvt_kernel<<<(n4 + 255) / 256, 256, 0, stream>>>(src, dst, n4);
  };
  cvt(x,   xb,   (size_t)MROWS * HID);
  cvt(Wh,  whb,  (size_t)NHEAD * HID);
  cvt(Wp1, wp1b, (size_t)512 * HID);
  cvt(Wt1, wt1b, (size_t)NW1 * 512);
  cvt(Wp2, wp2b, (size_t)256 * HID);
  cvt(Wt2, wt2b, (size_t)NW2 * 256);

  // head: 157 col tiles x 8 row tiles (mtile inner for B-panel L3 reuse)
  gemm_bt<0><<<dim3(8, 157), 256, 0, stream>>>(xb, whb, NHEAD, HID, out, nullptr, cluster, nullptr, nullptr, 0);
  // projections
  gemm_bt<1><<<dim3(8, 4), 256, 0, stream>>>(xb, wp1b, 512, HID, nullptr, p1b, nullptr, nullptr, nullptr, 0);
  gemm_bt<1><<<dim3(8, 2), 256, 0, stream>>>(xb, wp2b, 256, HID, nullptr, p2b, nullptr, nullptr, nullptr, 0);
  // tail stats passes (compute-only: per-tile max/sumexp, no logit writes)
  gemm_bt<2><<<dim3(8, 313), 256, 0, stream>>>(p1b, wt1b, NW1, 512, nullptr, nullptr, nullptr, stats1, nullptr, 0);
  gemm_bt<2><<<dim3(8, 1094), 256, 0, stream>>>(p2b, wt2b, NW2, 256, nullptr, nullptr, nullptr, stats2, nullptr, 0);
  // per-row merges -> scal[r] = cluster - m - log(sumexp)
  merge_stats<<<256, 256, 0, stream>>>(stats1, 313, cluster, 0, scal1);
  merge_stats<<<256, 256, 0, stream>>>(stats2, 1094, cluster, 1, scal2);
  // write passes: recompute tails, store normalized logits once
  gemm_bt<3><<<dim3(8, 313), 256, 0, stream>>>(p1b, wt1b, NW1, 512, out, nullptr, nullptr, nullptr, scal1, 20000);
  gemm_bt<3><<<dim3(8, 1094), 256, 0, stream>>>(p2b, wt2b, NW2, 256, out, nullptr, nullptr, nullptr, scal2, 60000);
}